// Round 2
// baseline (508.635 us; speedup 1.0000x reference)
//
#include <hip/hip_runtime.h>
#include <cmath>

namespace {

constexpr int R_ = 8, M1_ = 32, N1_ = 64, M2_ = 24, N2_ = 48;
constexpr int DIN = 768;          // M1*M2
constexpr int T_TOK = 4;          // tokens per workgroup
constexpr int NTHREADS = 512;     // 8 waves

// ---- LDS float offsets. All strides chosen so every wave access is <=2-way.
// Phase 1: XP + T1 double-buffer. Phase 2 (after barrier): HG + Z (overlap
// phase-1 regions). Phase 3: OUT overlaps dead HG.
constexpr int XP_F  = 0;      constexpr int XP_P = 98;    // [32][98]  = 3136
constexpr int T1A_F = 3136;                                // [32][194] = 6208
constexpr int T1B_F = 9344;   constexpr int T1_P = 194;   // [32][194] = 6208
constexpr int HG_F  = 0;      constexpr int HG_P = 192;   // [64][192] = 12288 (row-uniform access -> no pad needed)
constexpr int Z_F   = 12288;  constexpr int Z_P  = 194;   // [32][194] = 6208
constexpr int OUT_F = 0;      constexpr int OUT_P = 5;    // [768][5]  = 3840
constexpr int LDS_FLOATS = Z_F + M1_ * Z_P;               // 18496 floats = 73984 B

__global__ __launch_bounds__(NTHREADS, 4)
void kn_fused(const float* __restrict__ x,
              const float* __restrict__ A1,
              const float* __restrict__ B1,
              const float* __restrict__ A2,
              const float* __restrict__ B2,
              const float* __restrict__ b1,
              const float* __restrict__ b2,
              const int* __restrict__ p_inv,
              const int* __restrict__ q,
              float* __restrict__ out)
{
    extern __shared__ float lds[];
    const int tid  = threadIdx.x;
    const int lane = tid & 63;
    // wave id, forced uniform so all weight indices take the s_load path
    const int w = __builtin_amdgcn_readfirstlane(tid >> 6);   // 0..7

    const long tokBase = (long)blockIdx.x * T_TOK;

    // p_inv/q may be int64 or int32; a permutation can't have two zeros.
    const bool idx64 = (p_inv[1] == 0 && p_inv[3] == 0);

    // ---------------- fill XP: XP[i][k][t] = x[tok t][p_inv[i*24+k]] ---------
    {
        const int t   = tid >> 7;        // 0..3
        const int col = tid & 127;
        const float* xrow = x + (size_t)(tokBase + t) * DIN;
        #pragma unroll
        for (int c = 0; c < 6; ++c) {
            const int kIdx = c * 128 + col;
            const int pidx = idx64 ? p_inv[2 * kIdx] : p_inv[kIdx];
            lds[XP_F + (kIdx / M2_) * XP_P + (kIdx % M2_) * 4 + t] = xrow[pidx];
        }
    }

    const int il = lane >> 1;   // s1/sB row   (i or m1)
    const int tp = lane & 1;    // t-pair selector: t in {2tp, 2tp+1}

    // s1 compute: acc[jj][tt] = sum_k XP[il][k][2tp+tt] * B1[r][k][6w+jj]
    float acc[6][2];
    auto s1_compute = [&](int r) {
        #pragma unroll
        for (int a = 0; a < 6; ++a) { acc[a][0] = 0.f; acc[a][1] = 0.f; }
        const float* B1r = B1 + (size_t)r * M2_ * N2_ + 6 * w;   // uniform
        const int xb = XP_F + il * XP_P + 2 * tp;                // 8B aligned
        #pragma unroll 6
        for (int k = 0; k < M2_; ++k) {
            const float2 xv = *(const float2*)&lds[xb + 4 * k];
            #pragma unroll
            for (int jj = 0; jj < 6; ++jj) {
                const float bw = B1r[k * N2_ + jj];
                acc[jj][0] = fmaf(xv.x, bw, acc[jj][0]);
                acc[jj][1] = fmaf(xv.y, bw, acc[jj][1]);
            }
        }
    };
    auto s1_store = [&](int r) {
        float* t1n = lds + ((r & 1) ? T1B_F : T1A_F);
        const int tb = il * T1_P + 2 * tp;                       // 8B aligned
        #pragma unroll
        for (int jj = 0; jj < 6; ++jj) {
            float2 v; v.x = acc[jj][0]; v.y = acc[jj][1];
            *(float2*)&t1n[tb + (6 * w + jj) * 4] = v;
        }
    };

    // h accumulators: wave owns n1-octet [8w,8w+8); lane slot sid = lane+64s,
    // jt-linear: j = sid>>2, t = sid&3.  24 regs, live across all r.
    float hacc[8][3];
    #pragma unroll
    for (int a = 0; a < 8; ++a)
        #pragma unroll
        for (int s = 0; s < 3; ++s) hacc[a][s] = 0.f;

    __syncthreads();

    // ---------------- phase 1: one barrier per r (T1 double-buffered) --------
    s1_compute(0);
    s1_store(0);
    __syncthreads();
    for (int r = 0; r < R_; ++r) {
        // s2(r): hacc += A1_r * T1[buf r&1]
        const float* t1 = lds + ((r & 1) ? T1B_F : T1A_F);
        const float* A1r = A1 + ((size_t)r * N1_ + 8 * w) * M1_;  // uniform
        for (int i0 = 0; i0 < M1_; i0 += 4) {
            #pragma unroll
            for (int di = 0; di < 4; ++di) {
                const int i = i0 + di;
                float aw[8];
                #pragma unroll
                for (int nn = 0; nn < 8; ++nn) aw[nn] = A1r[nn * M1_ + i];
                float tv[3];
                #pragma unroll
                for (int s = 0; s < 3; ++s) tv[s] = t1[i * T1_P + lane + 64 * s];
                #pragma unroll
                for (int nn = 0; nn < 8; ++nn)
                    #pragma unroll
                    for (int s = 0; s < 3; ++s)
                        hacc[nn][s] = fmaf(aw[nn], tv[s], hacc[nn][s]);
            }
        }
        if (r + 1 < R_) {           // s1(r+1) overlaps s2(r) in this region
            s1_compute(r + 1);
            s1_store(r + 1);        // other buffer — no hazard with s2(r)
        }
        __syncthreads();
    }

    // ---------------- bias + GELU -> HG[n][sid] ------------------------------
    #pragma unroll
    for (int nn = 0; nn < 8; ++nn) {
        const int n = 8 * w + nn;
        #pragma unroll
        for (int s = 0; s < 3; ++s) {
            const int sid = lane + 64 * s;
            const float hv = hacc[nn][s] + b1[n * N2_ + (sid >> 2)];
            float g;
            if (__builtin_expect(fabsf(hv) < 0.04f, 1)) {
                // gelu(h) = 0.5h + sqrt(1/2pi) h^2 + O(h^4): exact to ~1e-10 rel here
                g = fmaf(0.3989422804f * hv, hv, 0.5f * hv);
            } else {
                g = 0.5f * hv * (1.0f + erff(hv * 0.70710678118654752f));
            }
            lds[HG_F + n * HG_P + sid] = g;
        }
    }
    __syncthreads();

    // ---------------- phase 2 (A-first): Z = A2_r * Hg ; out += Z * B2_r -----
    // sB' lane map: m1 = lane>>1, t = 2tp+u -> oacc[u][mm], m2 = 3w+mm.
    float oacc[2][3];
    #pragma unroll
    for (int u = 0; u < 2; ++u)
        #pragma unroll
        for (int mm = 0; mm < 3; ++mm) oacc[u][mm] = 0.f;

    float* Zp = lds + Z_F;
    const int zb = il * Z_P + 2 * tp;      // sB' read base (consecutive pair)

    for (int r = 0; r < R_; ++r) {
        // sA'(r): zacc[mm][s] = sum_n1 A2[r][4w+mm][n1] * Hg[n1][sid]
        float zacc[4][3];
        #pragma unroll
        for (int a = 0; a < 4; ++a)
            #pragma unroll
            for (int s = 0; s < 3; ++s) zacc[a][s] = 0.f;
        const float* A2r = A2 + ((size_t)r * M1_ + 4 * w) * N1_;   // uniform
        for (int k0 = 0; k0 < N1_; k0 += 4) {
            #pragma unroll
            for (int dk = 0; dk < 4; ++dk) {
                const int k = k0 + dk;
                float aw[4];
                #pragma unroll
                for (int mm = 0; mm < 4; ++mm) aw[mm] = A2r[mm * N1_ + k];
                float hvv[3];
                #pragma unroll
                for (int s = 0; s < 3; ++s) hvv[s] = lds[HG_F + k * HG_P + lane + 64 * s];
                #pragma unroll
                for (int mm = 0; mm < 4; ++mm)
                    #pragma unroll
                    for (int s = 0; s < 3; ++s)
                        zacc[mm][s] = fmaf(aw[mm], hvv[s], zacc[mm][s]);
            }
        }
        __syncthreads();    // previous sB' finished reading Z
        #pragma unroll
        for (int mm = 0; mm < 4; ++mm)
            #pragma unroll
            for (int s = 0; s < 3; ++s)
                Zp[(4 * w + mm) * Z_P + lane + 64 * s] = zacc[mm][s];
        __syncthreads();

        // sB'(r): oacc[u][mm] += Z[m1][n2,t] * B2[r][n2][3w+mm]
        const float* B2r = B2 + (size_t)r * N2_ * M2_ + 3 * w;     // uniform
        for (int k0 = 0; k0 < N2_; k0 += 4) {
            #pragma unroll
            for (int dk = 0; dk < 4; ++dk) {
                const int n2 = k0 + dk;
                const float z0 = Zp[zb + 4 * n2];
                const float z1 = Zp[zb + 4 * n2 + 1];
                #pragma unroll
                for (int mm = 0; mm < 3; ++mm) {
                    const float bw = B2r[n2 * M2_ + mm];
                    oacc[0][mm] = fmaf(z0, bw, oacc[0][mm]);
                    oacc[1][mm] = fmaf(z1, bw, oacc[1][mm]);
                }
            }
        }
        // loop wraps into sA'(r+1): same barrier-free region -> overlap
    }

    // ---------------- OUT[j768][t] = oacc (HG dead; Z untouched) -------------
    #pragma unroll
    for (int u = 0; u < 2; ++u)
        #pragma unroll
        for (int mm = 0; mm < 3; ++mm)
            lds[OUT_F + (il * M2_ + 3 * w + mm) * OUT_P + 2 * tp + u] = oacc[u][mm];
    __syncthreads();

    // ---------------- final: + b2, q-gather, coalesced store -----------------
    {
        const int t   = tid >> 7;
        const int col = tid & 127;
        float* orow = out + (size_t)(tokBase + t) * DIN;
        #pragma unroll
        for (int c = 0; c < 6; ++c) {
            const int j  = c * 128 + col;
            const int qj = idx64 ? q[2 * j] : q[j];
            orow[j] = lds[OUT_F + qj * OUT_P + t] + b2[qj];
        }
    }
}

} // namespace

extern "C" void kernel_launch(void* const* d_in, const int* in_sizes, int n_in,
                              void* d_out, int out_size, void* d_ws, size_t ws_size,
                              hipStream_t stream) {
    const float* x   = (const float*)d_in[0];
    const float* A1  = (const float*)d_in[1];
    const float* B1  = (const float*)d_in[2];
    const float* A2  = (const float*)d_in[3];
    const float* B2  = (const float*)d_in[4];
    const float* b1  = (const float*)d_in[5];
    const float* b2  = (const float*)d_in[6];
    const int*   piv = (const int*)d_in[7];
    const int*   q   = (const int*)d_in[8];
    float* out = (float*)d_out;

    const int tokens = in_sizes[0] / DIN;          // 4096
    const int grid   = tokens / T_TOK;             // 1024

    const size_t shmem = (size_t)LDS_FLOATS * sizeof(float);  // 73984 B
    (void)hipFuncSetAttribute((const void*)kn_fused,
                              hipFuncAttributeMaxDynamicSharedMemorySize,
                              (int)shmem);

    kn_fused<<<grid, NTHREADS, shmem, stream>>>(x, A1, B1, A2, B2, b1, b2, piv, q, out);
}

// Round 3
// 140.568 us; speedup vs baseline: 3.6184x; 3.6184x over previous
//
#include <hip/hip_runtime.h>
#include <cmath>

namespace {

typedef _Float16 half8_t __attribute__((ext_vector_type(8)));
typedef _Float16 half4_t __attribute__((ext_vector_type(4)));
typedef float    f32x4_t __attribute__((ext_vector_type(4)));

constexpr int R_ = 8, M1_ = 32, N1_ = 64, M2_ = 24, N2_ = 48;
constexpr int DIN = 768;          // M1*M2
constexpr int T_TOK = 4;          // tokens per workgroup
constexpr int NTHREADS = 512;     // 8 waves

// ---- d_ws f16 weight layout (element offsets). All *64 (2^6) scaled.
// Layouts are MFMA-fragment-native: A-op rows [m][k], B-op rows [n][k].
constexpr int W1_OFF = 0;         // [r][j=48][k=40]   = B1[r][k][j], k>=24 -> 0
constexpr int W2_OFF = 15360;     // [n1=64][rk=256]   = A1[r][n1][i]
constexpr int W3_OFF = 31744;     // [rm=256][n1=64]   = A2[r][m1][n1]
constexpr int W4_OFF = 48128;     // [m2=32][rk=384]   = B2[r][n2][m2], m2>=24 -> 0
constexpr int W_TOTAL = 60416;    // f16 elements (120832 B)

// ---- LDS layout. Phase A: XP + T1 dbuf. Phase B overlaps (barrier-ordered).
// f16-element offsets; strides are multiples of 8 f16 (16 B) for ds_read_b128,
// and give <=2-way bank aliasing (free).
constexpr int XP_H   = 0;         // [128][40]
constexpr int T1_H   = 5120;      // 2 x [192][40]
constexpr int T1_BUF = 7680;
constexpr int HG_H   = 0;         // [192][72]  (phase B)
constexpr int ZP_H   = 13824;     // [32][392]
constexpr int OUT_F  = 13184;     // f32-element offset: [768][9] f32
constexpr int LDS_BYTES = 80384;  // 2 blocks/CU (160768 <= 163840)

__global__ void prep_weights(const float* __restrict__ A1, const float* __restrict__ B1,
                             const float* __restrict__ A2, const float* __restrict__ B2,
                             _Float16* __restrict__ W)
{
    for (int idx = blockIdx.x * 256 + threadIdx.x; idx < W_TOTAL; idx += gridDim.x * 256) {
        float v;
        if (idx < W2_OFF) {                       // W1[r][j][k] = B1[r][k][j]*64
            int k = idx % 40, j = (idx / 40) % 48, r = idx / (40 * 48);
            v = (k < 24) ? B1[(r * 24 + k) * 48 + j] * 64.0f : 0.0f;
        } else if (idx < W3_OFF) {                // W2[n1][r*32+i] = A1[r][n1][i]*64
            int t = idx - W2_OFF;
            int rk = t & 255, n1 = t >> 8;
            v = A1[((rk >> 5) * 64 + n1) * 32 + (rk & 31)] * 64.0f;
        } else if (idx < W4_OFF) {                // W3[rm][n1] = A2 flat * 64
            int t = idx - W3_OFF;
            v = A2[t] * 64.0f;                    // [r*32+m1][n1] is A2's native order
        } else {                                  // W4[m2][r*48+n2] = B2[r][n2][m2]*64
            int t = idx - W4_OFF;
            int k = t % 384, m2 = t / 384;
            v = (m2 < 24) ? B2[k * 24 + m2] * 64.0f : 0.0f;
        }
        W[idx] = (_Float16)v;
    }
}

__global__ __launch_bounds__(NTHREADS, 4)
void kn_mfma(const float* __restrict__ x,
             const float* __restrict__ b1,
             const float* __restrict__ b2,
             const int* __restrict__ p_inv,
             const int* __restrict__ q,
             const _Float16* __restrict__ W,
             float* __restrict__ out)
{
    extern __shared__ char smem[];
    _Float16* ldsH = (_Float16*)smem;
    float*    ldsF = (float*)smem;

    const int tid  = threadIdx.x;
    const int lane = tid & 63;
    const int w    = __builtin_amdgcn_readfirstlane(tid >> 6);  // uniform wave id
    const int quad = lane >> 4;
    const int l16  = lane & 15;

    const long tokBase = (long)blockIdx.x * T_TOK;
    // p_inv/q may be int64 or int32; a permutation can't have two zeros.
    const bool idx64 = (p_inv[1] == 0 && p_inv[3] == 0);

    // ---------------- fill XPh[(t*32+i)][m2] = f16(x[t][p_inv[i*24+m2]]) -----
    {
        const int t = tid >> 7, col = tid & 127;
        const float* xrow = x + (size_t)(tokBase + t) * DIN;
        #pragma unroll
        for (int c = 0; c < 6; ++c) {
            const int kIdx = c * 128 + col;
            const int pidx = idx64 ? p_inv[2 * kIdx] : p_inv[kIdx];
            const int i = kIdx / 24, m2 = kIdx - i * 24;
            ldsH[XP_H + (t * 32 + i) * 40 + m2] = (_Float16)xrow[pidx];
        }
        // zero k-pad cols [24,40) so MFMA K=32 reads zeros beyond m2=24
        const int r0 = tid >> 2, c0 = 24 + (tid & 3) * 4;
        *(half4_t*)&ldsH[XP_H + r0 * 40 + c0] = half4_t{0, 0, 0, 0};
    }
    __syncthreads();

    const f32x4_t zero4 = {0.f, 0.f, 0.f, 0.f};

    // stage-1 A fragment is invariant across r: load once. A[m=(t,i)][k=m2]
    const half8_t xp_frag = *(const half8_t*)&ldsH[XP_H + (16 * w + l16) * 40 + quad * 8];
    const int s1_t  = (16 * w + quad * 4) >> 5;   // token (uniform per wave-half)
    const int s1_i0 = (16 * w + quad * 4) & 31;   // 4-aligned i base

    // stage-2 accumulators: h*2^12, 6 tiles/wave (row-tile w&3, cols (w>>2)+2u)
    f32x4_t hacc[6];
    #pragma unroll
    for (int u = 0; u < 6; ++u) hacc[u] = zero4;

    auto stage1 = [&](int rr) {   // T1_r[(t,i)][j] = XP * (B1_r*64), f16 out
        _Float16* t1 = ldsH + T1_H + (rr & 1) * T1_BUF;
        #pragma unroll
        for (int ct = 0; ct < 3; ++ct) {
            const half8_t bf = *(const half8_t*)&W[W1_OFF + (rr * 48 + ct * 16 + l16) * 40 + quad * 8];
            f32x4_t c = __builtin_amdgcn_mfma_f32_16x16x32_f16(xp_frag, bf, zero4, 0, 0, 0);
            half4_t p;
            p[0] = (_Float16)c[0]; p[1] = (_Float16)c[1];
            p[2] = (_Float16)c[2]; p[3] = (_Float16)c[3];
            const int s = s1_t * 48 + ct * 16 + l16;        // (t,j) row of T1T
            *(half4_t*)&t1[s * 40 + s1_i0] = p;             // 4 consecutive i
        }
    };

    auto stage2 = [&](int rr) {   // hacc += (A1_r*64) * T1_r
        const _Float16* t1 = ldsH + T1_H + (rr & 1) * T1_BUF;
        const half8_t af = *(const half8_t*)&W[W2_OFF + ((w & 3) * 16 + l16) * 256 + rr * 32 + quad * 8];
        #pragma unroll
        for (int u = 0; u < 6; ++u) {
            const int ct = (w >> 2) + 2 * u;
            const half8_t bf = *(const half8_t*)&t1[(ct * 16 + l16) * 40 + quad * 8];
            hacc[u] = __builtin_amdgcn_mfma_f32_16x16x32_f16(af, bf, hacc[u], 0, 0, 0);
        }
    };

    // ---------------- phase A: 1 barrier per r, T1 double-buffered -----------
    stage1(0);
    __syncthreads();
    for (int r = 0; r < R_; ++r) {
        stage2(r);
        if (r + 1 < R_) stage1(r + 1);
        __syncthreads();
    }

    // ---------------- epilogue 1: h = hacc/4096 + b1; Hg = gelu(h)*4096 ------
    {
        const float inv4096 = 1.0f / 4096.0f;
        #pragma unroll
        for (int u = 0; u < 6; ++u) {
            const int ct = (w >> 2) + 2 * u;
            const int s  = ct * 16 + l16;           // (t,n2)
            const int n2 = s % 48;
            const int n1b = (w & 3) * 16 + quad * 4;
            half4_t p;
            #pragma unroll
            for (int rg = 0; rg < 4; ++rg) {
                const float hv = hacc[u][rg] * inv4096 + b1[(n1b + rg) * 48 + n2];
                float g;
                if (__builtin_expect(fabsf(hv) < 0.04f, 1)) {
                    g = fmaf(0.3989422804f * hv, hv, 0.5f * hv);  // |err| = O(h^4)
                } else {
                    g = 0.5f * hv * (1.0f + erff(hv * 0.70710678118654752f));
                }
                p[rg] = (_Float16)(g * 4096.0f);
            }
            *(half4_t*)&ldsH[HG_H + s * 72 + n1b] = p;   // HgT[(t,n2)][n1]
        }
    }
    __syncthreads();

    // ---------------- phase B per token: Z' = (A2*64)*Hg' ; out += Z'*B2' ----
    const int kh  = w >> 2;        // stage-4 k-half (r 0..3 | 4..7)
    const int rt4 = (w >> 1) & 1;  // stage-4 m1 tile
    const int ct4 = w & 1;         // stage-4 m2 tile

    for (int tt = 0; tt < T_TOK; ++tt) {
        // stage 3: wave w owns r=w rows of Z'. 6 tiles x K=64.
        f32x4_t zc[6];
        #pragma unroll
        for (int u = 0; u < 6; ++u) zc[u] = zero4;
        #pragma unroll
        for (int e = 0; e < 2; ++e)
            #pragma unroll
            for (int ct = 0; ct < 3; ++ct) {
                const int u = e * 3 + ct;
                #pragma unroll
                for (int kk = 0; kk < 2; ++kk) {
                    const half8_t af = *(const half8_t*)&W[W3_OFF + ((2 * w + e) * 16 + l16) * 64 + kk * 32 + quad * 8];
                    const half8_t bf = *(const half8_t*)&ldsH[HG_H + (tt * 48 + ct * 16 + l16) * 72 + kk * 32 + quad * 8];
                    zc[u] = __builtin_amdgcn_mfma_f32_16x16x32_f16(af, bf, zc[u], 0, 0, 0);
                }
            }
        // scatter C -> A-layout Z'[m1][r*48+n2] (f16 writes; 2-way max)
        #pragma unroll
        for (int e = 0; e < 2; ++e)
            #pragma unroll
            for (int ct = 0; ct < 3; ++ct) {
                const int u = e * 3 + ct;
                const int kcol = w * 48 + ct * 16 + l16;
                #pragma unroll
                for (int rg = 0; rg < 4; ++rg)
                    ldsH[ZP_H + (16 * e + quad * 4 + rg) * 392 + kcol] = (_Float16)(zc[u][rg]);
            }
        __syncthreads();

        // stage 4: out''_t = Z' * B2'; wave = (kh, rt4, ct4); K-half = 192
        f32x4_t oc = zero4;
        #pragma unroll
        for (int kk = 0; kk < 6; ++kk) {
            const int k0 = kh * 192 + kk * 32;
            const half8_t af = *(const half8_t*)&ldsH[ZP_H + (rt4 * 16 + l16) * 392 + k0 + quad * 8];
            const half8_t bf = *(const half8_t*)&W[W4_OFF + (ct4 * 16 + l16) * 384 + k0 + quad * 8];
            oc = __builtin_amdgcn_mfma_f32_16x16x32_f16(af, bf, oc, 0, 0, 0);
        }
        const int m2c = ct4 * 16 + l16;
        if (m2c < 24) {
            #pragma unroll
            for (int rg = 0; rg < 4; ++rg) {
                const int m1 = rt4 * 16 + quad * 4 + rg;
                ldsF[OUT_F + (m1 * 24 + m2c) * 9 + tt * 2 + kh] = oc[rg];
            }
        }
        __syncthreads();   // protects Z' rewrite next tt, and final OUT reads
    }

    // ---------------- final: sum k-halves, /2^24, +b2, q-gather, store -------
    {
        const int t = tid >> 7, col = tid & 127;
        float* orow = out + (size_t)(tokBase + t) * DIN;
        const float sc = 1.0f / 16777216.0f;
        #pragma unroll
        for (int c = 0; c < 6; ++c) {
            const int j  = c * 128 + col;
            const int qj = idx64 ? q[2 * j] : q[j];
            orow[j] = (ldsF[OUT_F + qj * 9 + t * 2] + ldsF[OUT_F + qj * 9 + t * 2 + 1]) * sc + b2[qj];
        }
    }
}

} // namespace

extern "C" void kernel_launch(void* const* d_in, const int* in_sizes, int n_in,
                              void* d_out, int out_size, void* d_ws, size_t ws_size,
                              hipStream_t stream) {
    const float* x   = (const float*)d_in[0];
    const float* A1  = (const float*)d_in[1];
    const float* B1  = (const float*)d_in[2];
    const float* A2  = (const float*)d_in[3];
    const float* B2  = (const float*)d_in[4];
    const float* b1  = (const float*)d_in[5];
    const float* b2  = (const float*)d_in[6];
    const int*   piv = (const int*)d_in[7];
    const int*   q   = (const int*)d_in[8];
    float* out = (float*)d_out;
    _Float16* Wws = (_Float16*)d_ws;

    const int tokens = in_sizes[0] / DIN;          // 4096
    const int grid   = tokens / T_TOK;             // 1024

    prep_weights<<<128, 256, 0, stream>>>(A1, B1, A2, B2, Wws);

    (void)hipFuncSetAttribute((const void*)kn_mfma,
                              hipFuncAttributeMaxDynamicSharedMemorySize,
                              LDS_BYTES);
    kn_mfma<<<grid, NTHREADS, LDS_BYTES, stream>>>(x, b1, b2, piv, q, Wws, out);
}

// Round 4
// 139.186 us; speedup vs baseline: 3.6544x; 1.0099x over previous
//
#include <hip/hip_runtime.h>
#include <cmath>

namespace {

typedef _Float16 half8_t __attribute__((ext_vector_type(8)));
typedef _Float16 half4_t __attribute__((ext_vector_type(4)));
typedef float    f32x4_t __attribute__((ext_vector_type(4)));

constexpr int R_ = 8, M1_ = 32, N1_ = 64, M2_ = 24, N2_ = 48;
constexpr int DIN = 768;          // M1*M2
constexpr int T_TOK = 4;          // tokens per workgroup
constexpr int NTHREADS = 512;     // 8 waves

// ---- LDS layout. Phase A: XP + T1 dbuf. Phase B overlaps (barrier-ordered).
// f16-element offsets; strides are multiples of 8 f16 (16 B) for ds_read_b128,
// and give <=2-way bank aliasing (free).
constexpr int XP_H   = 0;         // [128][40]
constexpr int T1_H   = 5120;      // 2 x [192][40]
constexpr int T1_BUF = 7680;
constexpr int HG_H   = 0;         // [192][72]  (phase B)
constexpr int ZP_H   = 13824;     // [32][392]
constexpr int OUT_F  = 13184;     // f32-element offset: [768][9] f32
constexpr int LDS_BYTES = 80384;  // 2 blocks/CU (160768 <= 163840)

// 8 contiguous fp32 -> f16 fragment, scaled by 2^6 (exact)
__device__ inline half8_t cvt8c(const float* __restrict__ p) {
    const f32x4_t a = *(const f32x4_t*)p;
    const f32x4_t b = *(const f32x4_t*)(p + 4);
    half8_t h;
    #pragma unroll
    for (int i = 0; i < 4; ++i) {
        h[i]     = (_Float16)(a[i] * 64.0f);
        h[4 + i] = (_Float16)(b[i] * 64.0f);
    }
    return h;
}

__global__ __launch_bounds__(NTHREADS, 4)
void kn_mfma(const float* __restrict__ x,
             const float* __restrict__ A1,
             const float* __restrict__ B1,
             const float* __restrict__ A2,
             const float* __restrict__ B2,
             const float* __restrict__ b1,
             const float* __restrict__ b2,
             const int* __restrict__ p_inv,
             const int* __restrict__ q,
             float* __restrict__ out)
{
    extern __shared__ char smem[];
    _Float16* ldsH = (_Float16*)smem;
    float*    ldsF = (float*)smem;

    const int tid  = threadIdx.x;
    const int lane = tid & 63;
    const int w    = __builtin_amdgcn_readfirstlane(tid >> 6);  // uniform wave id
    const int quad = lane >> 4;
    const int l16  = lane & 15;

    const long tokBase = (long)blockIdx.x * T_TOK;
    // p_inv/q may be int64 or int32; a permutation can't have two zeros.
    const bool idx64 = (p_inv[1] == 0 && p_inv[3] == 0);

    // ---------------- fill XPh[(t*32+i)][m2] = f16(x[t][p_inv[i*24+m2]]) -----
    {
        const int t = tid >> 7, col = tid & 127;
        const float* xrow = x + (size_t)(tokBase + t) * DIN;
        #pragma unroll
        for (int c = 0; c < 6; ++c) {
            const int kIdx = c * 128 + col;
            const int pidx = idx64 ? p_inv[2 * kIdx] : p_inv[kIdx];
            const int i = kIdx / 24, m2 = kIdx - i * 24;
            ldsH[XP_H + (t * 32 + i) * 40 + m2] = (_Float16)xrow[pidx];
        }
        // zero k-pad cols [24,40) so MFMA K=32 reads zeros beyond m2=24
        const int r0 = tid >> 2, c0 = 24 + (tid & 3) * 4;
        *(half4_t*)&ldsH[XP_H + r0 * 40 + c0] = half4_t{0, 0, 0, 0};
    }
    __syncthreads();

    const f32x4_t zero4 = {0.f, 0.f, 0.f, 0.f};

    // stage-1 A fragment is invariant across r: load once. A[m=(t,i)][k=m2]
    const half8_t xp_frag = *(const half8_t*)&ldsH[XP_H + (16 * w + l16) * 40 + quad * 8];
    const int s1_t  = (16 * w + quad * 4) >> 5;   // token (uniform per wave-half)
    const int s1_i0 = (16 * w + quad * 4) & 31;   // 4-aligned i base

    // stage-2 accumulators: h*2^12, 6 tiles/wave (row-tile w&3, cols (w>>2)+2u)
    f32x4_t hacc[6];
    #pragma unroll
    for (int u = 0; u < 6; ++u) hacc[u] = zero4;

    auto stage1 = [&](int rr) {   // T1_r[(t,i)][j] = XP * (B1_r*64), f16 out
        _Float16* t1 = ldsH + T1_H + (rr & 1) * T1_BUF;
        #pragma unroll
        for (int ct = 0; ct < 3; ++ct) {
            // bf[n=j][k=m2]: B1 native is [r][k][j] -> 8 j-coalesced strided
            // dwords (4 x 64B segments per instr); k>=24 pad -> quad 3 zeroed.
            half8_t bf;
            #pragma unroll
            for (int z = 0; z < 8; ++z) bf[z] = (_Float16)0.f;
            if (quad < 3) {
                const float* p = B1 + ((size_t)rr * M2_ + quad * 8) * N2_ + ct * 16 + l16;
                #pragma unroll
                for (int kk = 0; kk < 8; ++kk)
                    bf[kk] = (_Float16)(p[kk * N2_] * 64.0f);
            }
            f32x4_t c = __builtin_amdgcn_mfma_f32_16x16x32_f16(xp_frag, bf, zero4, 0, 0, 0);
            half4_t pk;
            pk[0] = (_Float16)c[0]; pk[1] = (_Float16)c[1];
            pk[2] = (_Float16)c[2]; pk[3] = (_Float16)c[3];
            const int s = s1_t * 48 + ct * 16 + l16;        // (t,j) row of T1T
            *(half4_t*)&t1[s * 40 + s1_i0] = pk;            // 4 consecutive i
        }
    };

    auto stage2 = [&](int rr) {   // hacc += (A1_r*64) * T1_r
        const _Float16* t1 = ldsH + T1_H + (rr & 1) * T1_BUF;
        // af[n1][k=i]: A1 native [r][n1][i] is i-contiguous -> 2 dwordx4 + cvt
        const half8_t af = cvt8c(A1 + ((size_t)rr * N1_ + (w & 3) * 16 + l16) * M1_ + quad * 8);
        #pragma unroll
        for (int u = 0; u < 6; ++u) {
            const int ct = (w >> 2) + 2 * u;
            const half8_t bf = *(const half8_t*)&t1[(ct * 16 + l16) * 40 + quad * 8];
            hacc[u] = __builtin_amdgcn_mfma_f32_16x16x32_f16(af, bf, hacc[u], 0, 0, 0);
        }
    };

    // ---------------- phase A: 1 barrier per r, T1 double-buffered -----------
    stage1(0);
    __syncthreads();
    for (int r = 0; r < R_; ++r) {
        stage2(r);
        if (r + 1 < R_) stage1(r + 1);
        __syncthreads();
    }

    // ---------------- epilogue 1: h = hacc/4096 + b1; Hg = gelu(h)*4096 ------
    {
        const float inv4096 = 1.0f / 4096.0f;
        #pragma unroll
        for (int u = 0; u < 6; ++u) {
            const int ct = (w >> 2) + 2 * u;
            const int s  = ct * 16 + l16;           // (t,n2)
            const int n2 = s % 48;
            const int n1b = (w & 3) * 16 + quad * 4;
            half4_t p;
            #pragma unroll
            for (int rg = 0; rg < 4; ++rg) {
                const float hv = hacc[u][rg] * inv4096 + b1[(n1b + rg) * 48 + n2];
                float g;
                if (__builtin_expect(fabsf(hv) < 0.04f, 1)) {
                    g = fmaf(0.3989422804f * hv, hv, 0.5f * hv);  // |err| = O(h^4)
                } else {
                    g = 0.5f * hv * (1.0f + erff(hv * 0.70710678118654752f));
                }
                p[rg] = (_Float16)(g * 4096.0f);
            }
            *(half4_t*)&ldsH[HG_H + s * 72 + n1b] = p;   // HgT[(t,n2)][n1]
        }
    }

    // ---------------- hoisted phase-B weight fragments (register-resident) ---
    const int kh  = w >> 2;        // stage-4 k-half (r 0..3 | 4..7)
    const int rt4 = (w >> 1) & 1;  // stage-4 m1 tile
    const int ct4 = w & 1;         // stage-4 m2 tile

    // stage-3 af: A2 native [r][m1][n1] is n1-contiguous; wave w owns r=w.
    half8_t w3f[2][2];
    #pragma unroll
    for (int e = 0; e < 2; ++e)
        #pragma unroll
        for (int kk = 0; kk < 2; ++kk)
            w3f[e][kk] = cvt8c(A2 + ((size_t)w * M1_ + e * 16 + l16) * N1_ + kk * 32 + quad * 8);

    // stage-4 bf[m2][k=r*48+n2]: B2 native [r][n2][m2] -> strided dwords,
    // m2-coalesced across lanes; m2>=24 lanes zeroed (pad columns, discarded).
    half8_t w4f[6];
    {
        const int m2c = ct4 * 16 + l16;
        #pragma unroll
        for (int kk = 0; kk < 6; ++kk) {
            #pragma unroll
            for (int z = 0; z < 8; ++z) w4f[kk][z] = (_Float16)0.f;
            if (m2c < M2_) {
                const float* p = B2 + ((size_t)kh * 192 + kk * 32 + quad * 8) * M2_ + m2c;
                #pragma unroll
                for (int j2 = 0; j2 < 8; ++j2)
                    w4f[kk][j2] = (_Float16)(p[j2 * M2_] * 64.0f);
            }
        }
    }
    __syncthreads();

    // ---------------- phase B per token: Z' = (A2*64)*Hg' ; out += Z'*B2' ----
    for (int tt = 0; tt < T_TOK; ++tt) {
        // stage 3: wave w owns r=w rows of Z'. 6 tiles x K=64.
        f32x4_t zc[6];
        #pragma unroll
        for (int u = 0; u < 6; ++u) zc[u] = zero4;
        #pragma unroll
        for (int e = 0; e < 2; ++e)
            #pragma unroll
            for (int ct = 0; ct < 3; ++ct) {
                const int u = e * 3 + ct;
                #pragma unroll
                for (int kk = 0; kk < 2; ++kk) {
                    const half8_t bf = *(const half8_t*)&ldsH[HG_H + (tt * 48 + ct * 16 + l16) * 72 + kk * 32 + quad * 8];
                    zc[u] = __builtin_amdgcn_mfma_f32_16x16x32_f16(w3f[e][kk], bf, zc[u], 0, 0, 0);
                }
            }
        // scatter C -> A-layout Z'[m1][r*48+n2] (f16 writes; 2-way max)
        #pragma unroll
        for (int e = 0; e < 2; ++e)
            #pragma unroll
            for (int ct = 0; ct < 3; ++ct) {
                const int u = e * 3 + ct;
                const int kcol = w * 48 + ct * 16 + l16;
                #pragma unroll
                for (int rg = 0; rg < 4; ++rg)
                    ldsH[ZP_H + (16 * e + quad * 4 + rg) * 392 + kcol] = (_Float16)(zc[u][rg]);
            }
        __syncthreads();

        // stage 4: out''_t = Z' * B2'; wave = (kh, rt4, ct4); K-half = 192
        f32x4_t oc = zero4;
        #pragma unroll
        for (int kk = 0; kk < 6; ++kk) {
            const int k0 = kh * 192 + kk * 32;
            const half8_t af = *(const half8_t*)&ldsH[ZP_H + (rt4 * 16 + l16) * 392 + k0 + quad * 8];
            oc = __builtin_amdgcn_mfma_f32_16x16x32_f16(af, w4f[kk], oc, 0, 0, 0);
        }
        const int m2c = ct4 * 16 + l16;
        if (m2c < M2_) {
            #pragma unroll
            for (int rg = 0; rg < 4; ++rg) {
                const int m1 = rt4 * 16 + quad * 4 + rg;
                ldsF[OUT_F + (m1 * M2_ + m2c) * 9 + tt * 2 + kh] = oc[rg];
            }
        }
        __syncthreads();   // protects Z' rewrite next tt, and final OUT reads
    }

    // ---------------- final: sum k-halves, /2^24, +b2, q-gather, store -------
    {
        const int t = tid >> 7, col = tid & 127;
        float* orow = out + (size_t)(tokBase + t) * DIN;
        const float sc = 1.0f / 16777216.0f;
        #pragma unroll
        for (int c = 0; c < 6; ++c) {
            const int j  = c * 128 + col;
            const int qj = idx64 ? q[2 * j] : q[j];
            orow[j] = (ldsF[OUT_F + qj * 9 + t * 2] + ldsF[OUT_F + qj * 9 + t * 2 + 1]) * sc + b2[qj];
        }
    }
}

} // namespace

extern "C" void kernel_launch(void* const* d_in, const int* in_sizes, int n_in,
                              void* d_out, int out_size, void* d_ws, size_t ws_size,
                              hipStream_t stream) {
    const float* x   = (const float*)d_in[0];
    const float* A1  = (const float*)d_in[1];
    const float* B1  = (const float*)d_in[2];
    const float* A2  = (const float*)d_in[3];
    const float* B2  = (const float*)d_in[4];
    const float* b1  = (const float*)d_in[5];
    const float* b2  = (const float*)d_in[6];
    const int*   piv = (const int*)d_in[7];
    const int*   q   = (const int*)d_in[8];
    float* out = (float*)d_out;

    const int tokens = in_sizes[0] / DIN;          // 4096
    const int grid   = tokens / T_TOK;             // 1024

    (void)hipFuncSetAttribute((const void*)kn_mfma,
                              hipFuncAttributeMaxDynamicSharedMemorySize,
                              LDS_BYTES);
    kn_mfma<<<grid, NTHREADS, LDS_BYTES, stream>>>(x, A1, B1, A2, B2, b1, b2, piv, q, out);
}